// Round 2
// baseline (4290.754 us; speedup 1.0000x reference)
//
#include <hip/hip_runtime.h>
#include <cstdint>
#include <cmath>

#define S 2048
#define E 1024
#define NH 16
#define HD 64
#define KTOP 32

// ---------------- fp32 GEMM: C[M,N] = X[M,K] @ W[N,K]^T + bias ----------------
__global__ __launch_bounds__(256)
void gemm_xwT(const float* __restrict__ X, const float* __restrict__ W,
              const float* __restrict__ bias, float* __restrict__ C,
              int M, int N, int K) {
  __shared__ float Xs[16][68];
  __shared__ float Ws[16][68];
  const int bm = blockIdx.x * 64;
  const int bn = blockIdx.y * 64;
  const int tid = threadIdx.x;
  const int tx = tid & 15, ty = tid >> 4;
  const int r = tid & 63, kk = (tid >> 6) * 4;
  float acc[4][4] = {};
  for (int k0 = 0; k0 < K; k0 += 16) {
    __syncthreads();
    {
      float4 xv = *(const float4*)(X + (size_t)(bm + r) * K + k0 + kk);
      Xs[kk + 0][r] = xv.x; Xs[kk + 1][r] = xv.y;
      Xs[kk + 2][r] = xv.z; Xs[kk + 3][r] = xv.w;
      float4 wv4 = *(const float4*)(W + (size_t)(bn + r) * K + k0 + kk);
      Ws[kk + 0][r] = wv4.x; Ws[kk + 1][r] = wv4.y;
      Ws[kk + 2][r] = wv4.z; Ws[kk + 3][r] = wv4.w;
    }
    __syncthreads();
#pragma unroll
    for (int k = 0; k < 16; ++k) {
      float4 a = *(const float4*)&Xs[k][tx * 4];
      float4 b = *(const float4*)&Ws[k][ty * 4];
      float av[4] = {a.x, a.y, a.z, a.w};
      float bv[4] = {b.x, b.y, b.z, b.w};
#pragma unroll
      for (int i = 0; i < 4; ++i)
#pragma unroll
        for (int j = 0; j < 4; ++j)
          acc[i][j] = fmaf(av[i], bv[j], acc[i][j]);
    }
  }
  const float4 bv4 = *(const float4*)(bias + bn + ty * 4);
  const float bb[4] = {bv4.x, bv4.y, bv4.z, bv4.w};
#pragma unroll
  for (int i = 0; i < 4; ++i) {
    float4 o;
    o.x = acc[i][0] + bb[0];
    o.y = acc[i][1] + bb[1];
    o.z = acc[i][2] + bb[2];
    o.w = acc[i][3] + bb[3];
    *(float4*)(C + (size_t)(bm + tx * 4 + i) * N + bn + ty * 4) = o;
  }
}

// ------------- fp64-accumulate GEMM: C[M,N] = X[M,K] @ W[N,K]^T + b -----------
__global__ __launch_bounds__(256)
void gemm_xwT_f64(const float* __restrict__ X, const float* __restrict__ W,
                  const float* __restrict__ bias, double* __restrict__ C,
                  int M, int N, int K) {
  __shared__ float Xs[16][68];
  __shared__ float Ws[16][68];
  const int bm = blockIdx.x * 64;
  const int bn = blockIdx.y * 64;
  const int tid = threadIdx.x;
  const int tx = tid & 15, ty = tid >> 4;
  const int r = tid & 63, kk = (tid >> 6) * 4;
  double acc[4][4] = {};
  for (int k0 = 0; k0 < K; k0 += 16) {
    __syncthreads();
    {
      float4 xv = *(const float4*)(X + (size_t)(bm + r) * K + k0 + kk);
      Xs[kk + 0][r] = xv.x; Xs[kk + 1][r] = xv.y;
      Xs[kk + 2][r] = xv.z; Xs[kk + 3][r] = xv.w;
      float4 wv4 = *(const float4*)(W + (size_t)(bn + r) * K + k0 + kk);
      Ws[kk + 0][r] = wv4.x; Ws[kk + 1][r] = wv4.y;
      Ws[kk + 2][r] = wv4.z; Ws[kk + 3][r] = wv4.w;
    }
    __syncthreads();
#pragma unroll
    for (int k = 0; k < 16; ++k) {
      float4 a = *(const float4*)&Xs[k][tx * 4];
      float4 b = *(const float4*)&Ws[k][ty * 4];
      double av[4] = {a.x, a.y, a.z, a.w};
      double bv[4] = {b.x, b.y, b.z, b.w};
#pragma unroll
      for (int i = 0; i < 4; ++i)
#pragma unroll
        for (int j = 0; j < 4; ++j)
          acc[i][j] = fma(av[i], bv[j], acc[i][j]);
    }
  }
#pragma unroll
  for (int i = 0; i < 4; ++i)
#pragma unroll
    for (int j = 0; j < 4; ++j)
      C[(size_t)(bm + tx * 4 + i) * N + bn + ty * 4 + j] =
          acc[i][j] + (double)bias[bn + ty * 4 + j];
}

// ---------------- fused fp64 scores + exact top-32 + softmax + ctx ------------
__device__ __forceinline__ unsigned long long fordu64(double x) {
  unsigned long long u = (unsigned long long)__double_as_longlong(x);
  return (u & 0x8000000000000000ULL) ? ~u : (u | 0x8000000000000000ULL);
}

__global__ __launch_bounds__(256)
void attn_topk(const double* __restrict__ QP, const double* __restrict__ KP,
               const float* __restrict__ VP, float* __restrict__ CTX,
               float* __restrict__ AM) {
  __shared__ double Kt[64][65];   // pad 65: double2 reads ~2-way banked
  __shared__ double qs[16][65];
  const int h = blockIdx.y;
  const int r0 = blockIdx.x * 16;
  const int tid = threadIdx.x;
  const int lane = tid & 63, wid = tid >> 6;
  {
    const int f = tid * 4, rr = f >> 6, dd = f & 63;
    const double* src = QP + (size_t)(r0 + rr) * E + h * HD + dd;
    qs[rr][dd + 0] = src[0]; qs[rr][dd + 1] = src[1];
    qs[rr][dd + 2] = src[2]; qs[rr][dd + 3] = src[3];
  }
  // wave-distributed top-32 per row: lane i (<32) holds entry i
  double ev[4]; int ei[4];
  unsigned long long vminu[4]; int mpos[4];
#pragma unroll
  for (int rr = 0; rr < 4; ++rr) {
    ev[rr] = -INFINITY; ei[rr] = S - 1;
    vminu[rr] = fordu64(-INFINITY); mpos[rr] = 0;
  }
  const int rb = wid * 4;

  for (int c = 0; c < S / 64; ++c) {
    __syncthreads();
#pragma unroll
    for (int i = 0; i < 8; ++i) {
      const int f = tid * 2 + i * 512, j = f >> 6, dd = f & 63;
      *(double2*)&Kt[j][dd] =
          *(const double2*)(KP + (size_t)(c * 64 + j) * E + h * HD + dd);
    }
    __syncthreads();
    double a0 = 0, a1 = 0, a2 = 0, a3 = 0;
#pragma unroll
    for (int d2 = 0; d2 < 32; ++d2) {
      const double2 kv = *(const double2*)&Kt[lane][d2 * 2];
      const double2 q0 = *(const double2*)&qs[rb + 0][d2 * 2];
      const double2 q1 = *(const double2*)&qs[rb + 1][d2 * 2];
      const double2 q2 = *(const double2*)&qs[rb + 2][d2 * 2];
      const double2 q3 = *(const double2*)&qs[rb + 3][d2 * 2];
      a0 = fma(q0.x, kv.x, a0); a0 = fma(q0.y, kv.y, a0);
      a1 = fma(q1.x, kv.x, a1); a1 = fma(q1.y, kv.y, a1);
      a2 = fma(q2.x, kv.x, a2); a2 = fma(q2.y, kv.y, a2);
      a3 = fma(q3.x, kv.x, a3); a3 = fma(q3.y, kv.y, a3);
    }
    const double sc[4] = {a0 * 0.125, a1 * 0.125, a2 * 0.125, a3 * 0.125};
#pragma unroll
    for (int rr = 0; rr < 4; ++rr) {
      unsigned long long bal;
      if (c == 0) {
        // seed: lanes 0..31 take keys 0..31 as the initial list
        if (lane < KTOP) { ev[rr] = sc[rr]; ei[rr] = lane; }
        unsigned long long mk = (lane < KTOP) ? fordu64(ev[rr]) : ~0ULL;
        unsigned long long mu = mk;
#pragma unroll
        for (int off = 32; off; off >>= 1) {
          const unsigned long long o = __shfl_xor(mu, off);
          if (o < mu) mu = o;
        }
        vminu[rr] = mu;
        mpos[rr] = __ffsll(__ballot(mk == mu)) - 1;
        bal = __ballot(fordu64(sc[rr]) > vminu[rr]) & 0xFFFFFFFF00000000ULL;
      } else {
        bal = __ballot(fordu64(sc[rr]) > vminu[rr]);
      }
      while (bal) {
        const int b = __ffsll(bal) - 1;
        bal &= bal - 1;
        const double cv = __shfl(sc[rr], b);
        if (fordu64(cv) > vminu[rr]) {
          const int ci = c * 64 + b;
          if (lane == mpos[rr]) { ev[rr] = cv; ei[rr] = ci; }
          unsigned long long mk = (lane < KTOP) ? fordu64(ev[rr]) : ~0ULL;
          unsigned long long mu = mk;
#pragma unroll
          for (int off = 32; off; off >>= 1) {
            const unsigned long long o = __shfl_xor(mu, off);
            if (o < mu) mu = o;
          }
          vminu[rr] = mu;
          mpos[rr] = __ffsll(__ballot(mk == mu)) - 1;
        }
      }
    }
  }

  // softmax over exact fp64 top-32, attn_mean scatter, ctx (fp32)
#pragma unroll
  for (int rr = 0; rr < 4; ++rr) {
    const int row = r0 + rb + rr;
    const double v = (lane < KTOP) ? ev[rr] : -INFINITY;
    double m = v;
#pragma unroll
    for (int off = 32; off; off >>= 1) m = fmax(m, __shfl_xor(m, off));
    const double e = (lane < KTOP) ? exp(v - m) : 0.0;
    double z = e;
#pragma unroll
    for (int off = 32; off; off >>= 1) z += __shfl_xor(z, off);
    const float w = (float)(e / z);
    if (lane < KTOP) atomicAdd(AM + (size_t)row * S + ei[rr], w * 0.0625f);
    float acc = 0.f;
#pragma unroll
    for (int i = 0; i < KTOP; ++i) {
      const float wi = __shfl(w, i);
      const int ii = __shfl(ei[rr], i);
      acc = fmaf(wi, VP[(size_t)ii * E + h * HD + lane], acc);
    }
    CTX[(size_t)row * E + h * HD + lane] = acc;
  }
}

extern "C" void kernel_launch(void* const* d_in, const int* in_sizes, int n_in,
                              void* d_out, int out_size, void* d_ws, size_t ws_size,
                              hipStream_t stream) {
  const float* query = (const float*)d_in[0];
  const float* key   = (const float*)d_in[1];
  const float* value = (const float*)d_in[2];
  const float* wq = (const float*)d_in[3];
  const float* bq = (const float*)d_in[4];
  const float* wk = (const float*)d_in[5];
  const float* bk = (const float*)d_in[6];
  const float* wv = (const float*)d_in[7];
  const float* bv = (const float*)d_in[8];
  const float* wo = (const float*)d_in[9];
  const float* bo = (const float*)d_in[10];

  float* out = (float*)d_out;                 // [S, E]
  float* am  = out + (size_t)S * E;           // [S, S]
  double* qp = (double*)d_ws;                 // [S, E] fp64
  double* kp = qp + (size_t)S * E;            // [S, E] fp64
  float* vp  = (float*)(kp + (size_t)S * E);  // [S, E] fp32
  float* ctx = vp + (size_t)S * E;            // [S, E] fp32

  hipMemsetAsync(am, 0, (size_t)S * S * sizeof(float), stream);

  const dim3 gg(S / 64, E / 64), bb(256);
  gemm_xwT_f64<<<gg, bb, 0, stream>>>(query, wq, bq, qp, S, E, E);
  gemm_xwT_f64<<<gg, bb, 0, stream>>>(key,   wk, bk, kp, S, E, E);
  gemm_xwT<<<gg, bb, 0, stream>>>(value, wv, bv, vp, S, E, E);
  attn_topk<<<dim3(S / 16, NH), bb, 0, stream>>>(qp, kp, vp, ctx, am);
  gemm_xwT<<<gg, bb, 0, stream>>>(ctx, wo, bo, out, S, E, E);
}

// Round 3
// 4175.212 us; speedup vs baseline: 1.0277x; 1.0277x over previous
//
#include <hip/hip_runtime.h>
#include <cstdint>

#define S 2048
#define E 1024
#define NH 16
#define HD 64
#define KTOP 32
#define LSZ 40            // streamed candidate-list size (top-40 by fp32)
#define BANDU 1e-3f       // unscaled-score ambiguity band (~77 sigma of fp32 error)

// ---------------- fp32 GEMM: C[M,N] = X[M,K] @ W[N,K]^T + bias ----------------
__global__ __launch_bounds__(256)
void gemm_xwT(const float* __restrict__ X, const float* __restrict__ W,
              const float* __restrict__ bias, float* __restrict__ C,
              int M, int N, int K) {
  __shared__ float Xs[16][68];
  __shared__ float Ws[16][68];
  const int bm = blockIdx.x * 64;
  const int bn = blockIdx.y * 64;
  const int tid = threadIdx.x;
  const int tx = tid & 15, ty = tid >> 4;
  const int r = tid & 63, kk = (tid >> 6) * 4;
  float acc[4][4] = {};
  for (int k0 = 0; k0 < K; k0 += 16) {
    __syncthreads();
    {
      float4 xv = *(const float4*)(X + (size_t)(bm + r) * K + k0 + kk);
      Xs[kk + 0][r] = xv.x; Xs[kk + 1][r] = xv.y;
      Xs[kk + 2][r] = xv.z; Xs[kk + 3][r] = xv.w;
      float4 wv4 = *(const float4*)(W + (size_t)(bn + r) * K + k0 + kk);
      Ws[kk + 0][r] = wv4.x; Ws[kk + 1][r] = wv4.y;
      Ws[kk + 2][r] = wv4.z; Ws[kk + 3][r] = wv4.w;
    }
    __syncthreads();
#pragma unroll
    for (int k = 0; k < 16; ++k) {
      float4 a = *(const float4*)&Xs[k][tx * 4];
      float4 b = *(const float4*)&Ws[k][ty * 4];
      float av[4] = {a.x, a.y, a.z, a.w};
      float bv[4] = {b.x, b.y, b.z, b.w};
#pragma unroll
      for (int i = 0; i < 4; ++i)
#pragma unroll
        for (int j = 0; j < 4; ++j)
          acc[i][j] = fmaf(av[i], bv[j], acc[i][j]);
    }
  }
  const float4 bv4 = *(const float4*)(bias + bn + ty * 4);
  const float bb[4] = {bv4.x, bv4.y, bv4.z, bv4.w};
#pragma unroll
  for (int i = 0; i < 4; ++i) {
    float4 o;
    o.x = acc[i][0] + bb[0];
    o.y = acc[i][1] + bb[1];
    o.z = acc[i][2] + bb[2];
    o.w = acc[i][3] + bb[3];
    *(float4*)(C + (size_t)(bm + tx * 4 + i) * N + bn + ty * 4) = o;
  }
}

// ------------------------------ helpers --------------------------------------
__device__ __forceinline__ unsigned fordu(float x) {
  unsigned u = __float_as_uint(x);
  return (u & 0x80000000u) ? ~u : (u | 0x80000000u);
}
__device__ __forceinline__ float invfordu(unsigned f) {
  unsigned u = (f & 0x80000000u) ? (f ^ 0x80000000u) : ~f;
  return __uint_as_float(u);
}
__device__ __forceinline__ unsigned long long fordu64(double x) {
  unsigned long long u = (unsigned long long)__double_as_longlong(x);
  return (u >> 63) ? ~u : (u | 0x8000000000000000ULL);
}
__device__ __forceinline__ unsigned long long shflx64(unsigned long long v, int off) {
  int lo = __shfl_xor((int)(unsigned)(v & 0xFFFFFFFFULL), off);
  int hi = __shfl_xor((int)(unsigned)(v >> 32), off);
  return ((unsigned long long)(unsigned)hi << 32) | (unsigned)lo;
}
__device__ __forceinline__ double shflx_f64(double v, int off) {
  unsigned long long u = (unsigned long long)__double_as_longlong(v);
  return __longlong_as_double((long long)shflx64(u, off));
}
// fp64 projection element: sum_e x[e] * w[e], exact-to-fp64 (rare path)
__device__ double proj64(const float* __restrict__ xrow, const float* __restrict__ wrow) {
  double a0 = 0.0, a1 = 0.0;
  for (int e = 0; e < E; e += 8) {
    const float4 x0 = *(const float4*)(xrow + e);
    const float4 w0 = *(const float4*)(wrow + e);
    const float4 x1 = *(const float4*)(xrow + e + 4);
    const float4 w1 = *(const float4*)(wrow + e + 4);
    a0 = fma((double)x0.x, (double)w0.x, a0);
    a0 = fma((double)x0.y, (double)w0.y, a0);
    a0 = fma((double)x0.z, (double)w0.z, a0);
    a0 = fma((double)x0.w, (double)w0.w, a0);
    a1 = fma((double)x1.x, (double)w1.x, a1);
    a1 = fma((double)x1.y, (double)w1.y, a1);
    a1 = fma((double)x1.z, (double)w1.z, a1);
    a1 = fma((double)x1.w, (double)w1.w, a1);
  }
  return a0 + a1;
}

// ---------- fused fp32 scores + streamed top-40 + band-exact top-32 ----------
__global__ __launch_bounds__(256, 3)
void attn_topk(const float* __restrict__ QP, const float* __restrict__ KP,
               const float* __restrict__ VP,
               const float* __restrict__ QRAW, const float* __restrict__ KRAW,
               const float* __restrict__ WQ, const float* __restrict__ WK,
               float* __restrict__ CTX, float* __restrict__ AM) {
  __shared__ float Kt[128][64];   // XOR-swizzled float4 slots: slot' = j ^ (l&7)
  __shared__ float qs[16][64];    // broadcast-read, linear
  const int h = blockIdx.y;
  const int r0 = blockIdx.x * 16;
  const int tid = threadIdx.x;
  const int lane = tid & 63, wid = tid >> 6, rb = wid * 4;

  { // stage q rows
    const int rr = tid >> 4, dd = (tid & 15) * 4;
    *(float4*)&qs[rr][dd] = *(const float4*)(QP + (size_t)(r0 + rr) * E + h * HD + dd);
  }

  float ev[4]; int ei[4]; unsigned vmin[4]; int mpos[4];
#pragma unroll
  for (int rr = 0; rr < 4; ++rr) { ev[rr] = -INFINITY; ei[rr] = 0; vmin[rr] = 0u; mpos[rr] = 0; }

  for (int c = 0; c < S / 128; ++c) {
    __syncthreads();
#pragma unroll
    for (int i = 0; i < 8; ++i) {   // stage 128x64 fp32 K tile, swizzled
      const int flat = tid + i * 256, l = flat >> 4, j = flat & 15;
      *(float4*)&Kt[l][(j ^ (l & 7)) * 4] =
          *(const float4*)(KP + (size_t)(c * 128 + l) * E + h * HD + j * 4);
    }
    __syncthreads();

    float sA[4] = {0.f, 0.f, 0.f, 0.f}, sB[4] = {0.f, 0.f, 0.f, 0.f};
#pragma unroll
    for (int d4 = 0; d4 < 16; ++d4) {
      const float4 kA = *(const float4*)&Kt[lane][(d4 ^ (lane & 7)) * 4];
      const float4 kB = *(const float4*)&Kt[lane + 64][(d4 ^ (lane & 7)) * 4];
#pragma unroll
      for (int rr = 0; rr < 4; ++rr) {
        const float4 q = *(const float4*)&qs[rb + rr][d4 * 4];
        sA[rr] = fmaf(q.x, kA.x, sA[rr]); sA[rr] = fmaf(q.y, kA.y, sA[rr]);
        sA[rr] = fmaf(q.z, kA.z, sA[rr]); sA[rr] = fmaf(q.w, kA.w, sA[rr]);
        sB[rr] = fmaf(q.x, kB.x, sB[rr]); sB[rr] = fmaf(q.y, kB.y, sB[rr]);
        sB[rr] = fmaf(q.z, kB.z, sB[rr]); sB[rr] = fmaf(q.w, kB.w, sB[rr]);
      }
    }

    const int cbase = c * 128;
#pragma unroll
    for (int rr = 0; rr < 4; ++rr) {
      unsigned long long balA, balB;
      if (c == 0) {
        if (lane < LSZ) { ev[rr] = sA[rr]; ei[rr] = lane; }
        unsigned mk = (lane < LSZ) ? fordu(ev[rr]) : 0xFFFFFFFFu, mu = mk;
#pragma unroll
        for (int off = 32; off; off >>= 1) mu = min(mu, (unsigned)__shfl_xor((int)mu, off));
        vmin[rr] = mu; mpos[rr] = __ffsll(__ballot(mk == mu)) - 1;
        balA = __ballot(fordu(sA[rr]) > vmin[rr]) & ~((1ULL << LSZ) - 1ULL);
        balB = __ballot(fordu(sB[rr]) > vmin[rr]);
      } else {
        balA = __ballot(fordu(sA[rr]) > vmin[rr]);
        balB = __ballot(fordu(sB[rr]) > vmin[rr]);
      }
      while (balA | balB) {
        float cv; int ci;
        if (balA) { int b = __ffsll(balA) - 1; balA &= balA - 1; cv = __shfl(sA[rr], b); ci = cbase + b; }
        else      { int b = __ffsll(balB) - 1; balB &= balB - 1; cv = __shfl(sB[rr], b); ci = cbase + 64 + b; }
        if (fordu(cv) > vmin[rr]) {          // recheck vs updated min
          if (lane == mpos[rr]) { ev[rr] = cv; ei[rr] = ci; }
          unsigned mk = (lane < LSZ) ? fordu(ev[rr]) : 0xFFFFFFFFu, mu = mk;
#pragma unroll
          for (int off = 32; off; off >>= 1) mu = min(mu, (unsigned)__shfl_xor((int)mu, off));
          vmin[rr] = mu; mpos[rr] = __ffsll(__ballot(mk == mu)) - 1;
        }
      }
    }
  }

  // ------------------------------ epilogue ------------------------------
#pragma unroll
  for (int rr = 0; rr < 4; ++rr) {
    const int row = r0 + rb + rr;
    unsigned long long key = (lane < LSZ)
        ? (((unsigned long long)fordu(ev[rr])) << 32) | (unsigned)(2047 - ei[rr])
        : 0ULL;
    // bitonic sort, descending, 64 lanes
#pragma unroll
    for (int k = 2; k <= 64; k <<= 1)
#pragma unroll
      for (int j = k >> 1; j; j >>= 1) {
        const unsigned long long o = shflx64(key, j);
        const unsigned long long mx = key > o ? key : o;
        const unsigned long long mn = key > o ? o : key;
        const bool up = ((lane & k) == 0);
        key = (((lane & j) == 0) == up) ? mx : mn;
      }
    const float v = invfordu((unsigned)(key >> 32));
    const int idx = 2047 - (int)(key & 0xFFFFFFFFu);
    const float v32 = __shfl(v, 31), v33 = __shfl(v, 32);
    bool IN = (lane < KTOP);

    if (v32 - v33 <= BANDU) {   // ambiguous cut (rare, wave-uniform)
      const bool flg = (lane < LSZ) && (v <= v33 + BANDU) && (v >= v32 - BANDU);
      const unsigned long long fmask = __ballot(flg);
      const int nAbove = __popcll(__ballot((lane < KTOP) && !flg));
      const int need = KTOP - nAbove;
      // exact fp64 q for this row (lane = head dim)
      const double qd = proj64(QRAW + (size_t)row * E, WQ + (size_t)(h * HD + lane) * E);
      double s64 = -INFINITY;
      unsigned long long t = fmask;
      while (t) {
        const int f = __ffsll(t) - 1; t &= t - 1;
        const int ki = __shfl(idx, f);
        const double kd = proj64(KRAW + (size_t)ki * E, WK + (size_t)(h * HD + lane) * E);
        double sacc = qd * kd;
#pragma unroll
        for (int off = 32; off; off >>= 1) sacc += shflx_f64(sacc, off);
        if (lane == f) s64 = sacc;
      }
      bool in2 = false;
      for (int t2 = 0; t2 < need; ++t2) {
        const unsigned long long sk = (flg && !in2) ? fordu64(s64) : 0ULL;
        unsigned long long mx = sk;
#pragma unroll
        for (int off = 32; off; off >>= 1) { const unsigned long long o = shflx64(mx, off); if (o > mx) mx = o; }
        const unsigned long long wb = __ballot(flg && !in2 && sk == mx);
        if (lane == __ffsll(wb) - 1) in2 = true;
      }
      IN = ((lane < KTOP) && !flg) || in2;
    }

    // softmax over IN (scores unscaled; scale by 1/8 inside exp)
    float x = IN ? v : -INFINITY, m = x;
#pragma unroll
    for (int off = 32; off; off >>= 1) m = fmaxf(m, __shfl_xor(m, off));
    const float ee = IN ? expf((v - m) * 0.125f) : 0.f;
    float z = ee;
#pragma unroll
    for (int off = 32; off; off >>= 1) z += __shfl_xor(z, off);
    const float w = ee / z;
    if (IN) atomicAdd(AM + (size_t)row * S + idx, w * 0.0625f);

    unsigned long long mask = __ballot(IN);
    float acc = 0.f;
    while (mask) {
      const int b = __ffsll(mask) - 1; mask &= mask - 1;
      const float wi = __shfl(w, b);
      const int ii = __shfl(idx, b);
      acc = fmaf(wi, VP[(size_t)ii * E + h * HD + lane], acc);
    }
    CTX[(size_t)row * E + h * HD + lane] = acc;
  }
}

extern "C" void kernel_launch(void* const* d_in, const int* in_sizes, int n_in,
                              void* d_out, int out_size, void* d_ws, size_t ws_size,
                              hipStream_t stream) {
  const float* query = (const float*)d_in[0];
  const float* key   = (const float*)d_in[1];
  const float* value = (const float*)d_in[2];
  const float* wq = (const float*)d_in[3];
  const float* bq = (const float*)d_in[4];
  const float* wk = (const float*)d_in[5];
  const float* bk = (const float*)d_in[6];
  const float* wv = (const float*)d_in[7];
  const float* bv = (const float*)d_in[8];
  const float* wo = (const float*)d_in[9];
  const float* bo = (const float*)d_in[10];

  float* out = (float*)d_out;                 // [S, E]
  float* am  = out + (size_t)S * E;           // [S, S]
  float* qp  = (float*)d_ws;                  // [S, E]
  float* kp  = qp + (size_t)S * E;
  float* vp  = kp + (size_t)S * E;
  float* ctx = vp + (size_t)S * E;

  hipMemsetAsync(am, 0, (size_t)S * S * sizeof(float), stream);

  const dim3 gg(S / 64, E / 64), bb(256);
  gemm_xwT<<<gg, bb, 0, stream>>>(query, wq, bq, qp, S, E, E);
  gemm_xwT<<<gg, bb, 0, stream>>>(key,   wk, bk, kp, S, E, E);
  gemm_xwT<<<gg, bb, 0, stream>>>(value, wv, bv, vp, S, E, E);
  attn_topk<<<dim3(S / 16, NH), bb, 0, stream>>>(qp, kp, vp, query, key, wq, wk, ctx, am);
  gemm_xwT<<<gg, bb, 0, stream>>>(ctx, wo, bo, out, S, E, E);
}

// Round 4
// 988.868 us; speedup vs baseline: 4.3391x; 4.2222x over previous
//
#include <hip/hip_runtime.h>
#include <cstdint>

#define S 2048
#define E 1024
#define NH 16
#define HD 64
#define KTOP 32
#define BANDU 1e-3f       // unscaled-score ambiguity band (~77 sigma of fp32 err)
#define NPMAX 48

// ---------------- fp32 GEMM: C[M,N] = X[M,K] @ W[N,K]^T + bias ----------------
__global__ __launch_bounds__(256)
void gemm_xwT(const float* __restrict__ X, const float* __restrict__ W,
              const float* __restrict__ bias, float* __restrict__ C,
              int M, int N, int K) {
  __shared__ float Xs[16][68];
  __shared__ float Ws[16][68];
  const int bm = blockIdx.x * 64;
  const int bn = blockIdx.y * 64;
  const int tid = threadIdx.x;
  const int tx = tid & 15, ty = tid >> 4;
  const int r = tid & 63, kk = (tid >> 6) * 4;
  float acc[4][4] = {};
  for (int k0 = 0; k0 < K; k0 += 16) {
    __syncthreads();
    {
      float4 xv = *(const float4*)(X + (size_t)(bm + r) * K + k0 + kk);
      Xs[kk + 0][r] = xv.x; Xs[kk + 1][r] = xv.y;
      Xs[kk + 2][r] = xv.z; Xs[kk + 3][r] = xv.w;
      float4 wv4 = *(const float4*)(W + (size_t)(bn + r) * K + k0 + kk);
      Ws[kk + 0][r] = wv4.x; Ws[kk + 1][r] = wv4.y;
      Ws[kk + 2][r] = wv4.z; Ws[kk + 3][r] = wv4.w;
    }
    __syncthreads();
#pragma unroll
    for (int k = 0; k < 16; ++k) {
      float4 a = *(const float4*)&Xs[k][tx * 4];
      float4 b = *(const float4*)&Ws[k][ty * 4];
      float av[4] = {a.x, a.y, a.z, a.w};
      float bv[4] = {b.x, b.y, b.z, b.w};
#pragma unroll
      for (int i = 0; i < 4; ++i)
#pragma unroll
        for (int j = 0; j < 4; ++j)
          acc[i][j] = fmaf(av[i], bv[j], acc[i][j]);
    }
  }
  const float4 bv4 = *(const float4*)(bias + bn + ty * 4);
  const float bb[4] = {bv4.x, bv4.y, bv4.z, bv4.w};
#pragma unroll
  for (int i = 0; i < 4; ++i) {
    float4 o;
    o.x = acc[i][0] + bb[0];
    o.y = acc[i][1] + bb[1];
    o.z = acc[i][2] + bb[2];
    o.w = acc[i][3] + bb[3];
    *(float4*)(C + (size_t)(bm + tx * 4 + i) * N + bn + ty * 4) = o;
  }
}

// -------- score GEMM per head: Sc[hz][i][j] = Q_h[i,:].K_h[j,:], K=64 ---------
__global__ __launch_bounds__(256)
void score_qkT(const float* __restrict__ QP, const float* __restrict__ KP,
               float* __restrict__ Sc, int h0) {
  const float* A = QP + (size_t)(h0 + blockIdx.z) * HD;
  const float* B = KP + (size_t)(h0 + blockIdx.z) * HD;
  float* C = Sc + (size_t)blockIdx.z * S * S;
  __shared__ float Xs[16][68];
  __shared__ float Ws[16][68];
  const int bm = blockIdx.x * 64;
  const int bn = blockIdx.y * 64;
  const int tid = threadIdx.x;
  const int tx = tid & 15, ty = tid >> 4;
  const int r = tid & 63, kk = (tid >> 6) * 4;
  float acc[4][4] = {};
#pragma unroll
  for (int k0 = 0; k0 < HD; k0 += 16) {
    __syncthreads();
    {
      float4 xv = *(const float4*)(A + (size_t)(bm + r) * E + k0 + kk);
      Xs[kk + 0][r] = xv.x; Xs[kk + 1][r] = xv.y;
      Xs[kk + 2][r] = xv.z; Xs[kk + 3][r] = xv.w;
      float4 wv4 = *(const float4*)(B + (size_t)(bn + r) * E + k0 + kk);
      Ws[kk + 0][r] = wv4.x; Ws[kk + 1][r] = wv4.y;
      Ws[kk + 2][r] = wv4.z; Ws[kk + 3][r] = wv4.w;
    }
    __syncthreads();
#pragma unroll
    for (int k = 0; k < 16; ++k) {
      float4 a = *(const float4*)&Xs[k][tx * 4];
      float4 b = *(const float4*)&Ws[k][ty * 4];
      float av[4] = {a.x, a.y, a.z, a.w};
      float bv[4] = {b.x, b.y, b.z, b.w};
#pragma unroll
      for (int i = 0; i < 4; ++i)
#pragma unroll
        for (int j = 0; j < 4; ++j)
          acc[i][j] = fmaf(av[i], bv[j], acc[i][j]);
    }
  }
#pragma unroll
  for (int i = 0; i < 4; ++i) {
    float4 o;
    o.x = acc[i][0]; o.y = acc[i][1]; o.z = acc[i][2]; o.w = acc[i][3];
    *(float4*)(C + (size_t)(bm + tx * 4 + i) * S + bn + ty * 4) = o;
  }
}

// ------------------------------ helpers --------------------------------------
__device__ __forceinline__ unsigned long long fordu64(double x) {
  unsigned long long u = (unsigned long long)__double_as_longlong(x);
  return (u >> 63) ? ~u : (u | 0x8000000000000000ULL);
}
__device__ __forceinline__ unsigned long long shflx64(unsigned long long v, int off) {
  int lo = __shfl_xor((int)(unsigned)(v & 0xFFFFFFFFULL), off);
  int hi = __shfl_xor((int)(unsigned)(v >> 32), off);
  return ((unsigned long long)(unsigned)hi << 32) | (unsigned)lo;
}
__device__ __forceinline__ double shflx_f64(double v, int off) {
  unsigned long long u = (unsigned long long)__double_as_longlong(v);
  return __longlong_as_double((long long)shflx64(u, off));
}
// fp64 projection element: sum_e x[e]*w[e] (rare band path)
__device__ double proj64(const float* __restrict__ xrow, const float* __restrict__ wrow) {
  double a0 = 0.0, a1 = 0.0;
  for (int e = 0; e < E; e += 8) {
    const float4 x0 = *(const float4*)(xrow + e);
    const float4 w0 = *(const float4*)(wrow + e);
    const float4 x1 = *(const float4*)(xrow + e + 4);
    const float4 w1 = *(const float4*)(wrow + e + 4);
    a0 = fma((double)x0.x, (double)w0.x, a0);
    a0 = fma((double)x0.y, (double)w0.y, a0);
    a0 = fma((double)x0.z, (double)w0.z, a0);
    a0 = fma((double)x0.w, (double)w0.w, a0);
    a1 = fma((double)x1.x, (double)w1.x, a1);
    a1 = fma((double)x1.y, (double)w1.y, a1);
    a1 = fma((double)x1.z, (double)w1.z, a1);
    a1 = fma((double)x1.w, (double)w1.w, a1);
  }
  return a0 + a1;
}

// ---------- select: exact fp32 pop-max top-k + band fp64 + softmax + ctx ------
__global__ __launch_bounds__(256)
void select_rows(const float* __restrict__ Sc, const float* __restrict__ VP,
                 const float* __restrict__ QRAW, const float* __restrict__ KRAW,
                 const float* __restrict__ WQ, const float* __restrict__ WK,
                 float* __restrict__ CTX, float* __restrict__ AM, int h0) {
  const int h = h0 + blockIdx.y;
  const int row = blockIdx.x * 4 + (threadIdx.x >> 6);
  const int lane = threadIdx.x & 63;
  const float* srow = Sc + (size_t)blockIdx.y * S * S + (size_t)row * S;

  // lane holds 32 scores: idx(i,c) = i*256 + lane*4 + c  (coalesced float4)
  float4 g[8];
#pragma unroll
  for (int i = 0; i < 8; ++i) g[i] = *(const float4*)(srow + i * 256 + lane * 4);
  float gm[8];
#pragma unroll
  for (int i = 0; i < 8; ++i)
    gm[i] = fmaxf(fmaxf(g[i].x, g[i].y), fmaxf(g[i].z, g[i].w));
  float lm = gm[0];
#pragma unroll
  for (int i = 1; i < 8; ++i) lm = fmaxf(lm, gm[i]);

  float mv = -INFINITY; int mi = 0;
  float v32 = -INFINITY, v33 = -INFINITY;
  bool stop = false;

#pragma unroll 1
  for (int p = 0; p < NPMAX && !stop; ++p) {
    // wave max
    float M = lm;
#pragma unroll
    for (int off = 32; off; off >>= 1) M = fmaxf(M, __shfl_xor(M, off));
    // first (lowest-idx) position of M within each lane's slice
    int fp = 0x7FFFFFFF;
#pragma unroll
    for (int i = 7; i >= 0; --i) {
      const int b = i * 256 + lane * 4;
      if (g[i].w == M) fp = b + 3;
      if (g[i].z == M) fp = b + 2;
      if (g[i].y == M) fp = b + 1;
      if (g[i].x == M) fp = b + 0;
    }
    const unsigned long long bal = __ballot(lm == M);
    int widx;
    if (__popcll(bal) == 1) {
      widx = __shfl(fp, __ffsll(bal) - 1);
    } else {                      // cross-lane value tie: min global idx wins
      int c2 = (lm == M) ? fp : 0x7FFFFFFF;
#pragma unroll
      for (int off = 32; off; off >>= 1) c2 = min(c2, __shfl_xor(c2, off));
      widx = c2;
    }
    // clear popped slot (og, oc wave-uniform; ol per-lane predicate)
    const int ol = (widx >> 2) & 63, og = widx >> 8, oc = widx & 3;
    const bool own = (lane == ol);
#pragma unroll
    for (int i = 0; i < 8; ++i)
      if (og == i && own) {
        if (oc == 0) g[i].x = -INFINITY;
        else if (oc == 1) g[i].y = -INFINITY;
        else if (oc == 2) g[i].z = -INFINITY;
        else g[i].w = -INFINITY;
        gm[i] = fmaxf(fmaxf(g[i].x, g[i].y), fmaxf(g[i].z, g[i].w));
      }
    float m8 = gm[0];
#pragma unroll
    for (int i = 1; i < 8; ++i) m8 = fmaxf(m8, gm[i]);
    lm = own ? m8 : lm;

    if (lane == p) { mv = M; mi = widx; }
    if (p == 33) {
      v32 = __shfl(mv, 31); v33 = __shfl(mv, 32);
      stop = (v32 - v33 > BANDU);
    } else if (p > 33) {
      stop = (M < v32 - BANDU);
    }
  }

  bool IN = (lane < KTOP);
  if (v32 - v33 <= BANDU) {   // ambiguous cut (rare, wave-uniform)
    const bool flg = (mv >= v32 - BANDU) && (mv <= v33 + BANDU);
    const unsigned long long fmask = __ballot(flg);
    const int nAbove = __popcll(__ballot((lane < KTOP) && !flg));
    const int need = KTOP - nAbove;
    const double qd = proj64(QRAW + (size_t)row * E, WQ + (size_t)(h * HD + lane) * E);
    double s64 = -INFINITY;
    unsigned long long t = fmask;
    while (t) {
      const int f = __ffsll(t) - 1; t &= t - 1;
      const int ki = __shfl(mi, f);
      const double kd = proj64(KRAW + (size_t)ki * E, WK + (size_t)(h * HD + lane) * E);
      double sacc = qd * kd;
#pragma unroll
      for (int off = 32; off; off >>= 1) sacc += shflx_f64(sacc, off);
      if (lane == f) s64 = sacc;
    }
    bool in2 = false;
    for (int t2 = 0; t2 < need; ++t2) {
      const unsigned long long sk = (flg && !in2) ? fordu64(s64) : 0ULL;
      unsigned long long mx = sk;
#pragma unroll
      for (int off = 32; off; off >>= 1) {
        const unsigned long long o = shflx64(mx, off);
        if (o > mx) mx = o;
      }
      const unsigned long long wb = __ballot(flg && !in2 && sk == mx);
      if (lane == __ffsll(wb) - 1) in2 = true;
    }
    IN = ((lane < KTOP) && !flg) || in2;
  }

  // softmax over IN (unscaled scores; scale 1/8 inside exp)
  float x = IN ? mv : -INFINITY, m = x;
#pragma unroll
  for (int off = 32; off; off >>= 1) m = fmaxf(m, __shfl_xor(m, off));
  const float ee = IN ? expf((mv - m) * 0.125f) : 0.f;
  float z = ee;
#pragma unroll
  for (int off = 32; off; off >>= 1) z += __shfl_xor(z, off);
  const float w = ee / z;
  if (IN) atomicAdd(AM + (size_t)row * S + mi, w * 0.0625f);

  unsigned long long mask = __ballot(IN);
  float acc = 0.f;
  while (mask) {
    const int b = __ffsll(mask) - 1; mask &= mask - 1;
    const float wi = __shfl(w, b);
    const int ii = __shfl(mi, b);
    acc = fmaf(wi, VP[(size_t)ii * E + h * HD + lane], acc);
  }
  CTX[(size_t)row * E + h * HD + lane] = acc;
}

extern "C" void kernel_launch(void* const* d_in, const int* in_sizes, int n_in,
                              void* d_out, int out_size, void* d_ws, size_t ws_size,
                              hipStream_t stream) {
  const float* query = (const float*)d_in[0];
  const float* key   = (const float*)d_in[1];
  const float* value = (const float*)d_in[2];
  const float* wq = (const float*)d_in[3];
  const float* bq = (const float*)d_in[4];
  const float* wk = (const float*)d_in[5];
  const float* bk = (const float*)d_in[6];
  const float* wv = (const float*)d_in[7];
  const float* bv = (const float*)d_in[8];
  const float* wo = (const float*)d_in[9];
  const float* bo = (const float*)d_in[10];

  float* out = (float*)d_out;                 // [S, E]
  float* am  = out + (size_t)S * E;           // [S, S]
  float* qp  = (float*)d_ws;                  // [S, E]
  float* kp  = qp + (size_t)S * E;
  float* vp  = kp + (size_t)S * E;
  float* ctx = vp + (size_t)S * E;
  float* sc  = ctx + (size_t)S * E;           // score buffer (chunked by heads)

  // heads per chunk, limited by remaining workspace (>=48MB known good)
  const size_t base = 4ull * S * E * sizeof(float);
  const size_t per_head = (size_t)S * S * sizeof(float);
  int nhb = (ws_size > base) ? (int)((ws_size - base) / per_head) : 0;
  if (nhb < 1) nhb = 1;
  if (nhb > NH) nhb = NH;

  hipMemsetAsync(am, 0, (size_t)S * S * sizeof(float), stream);

  const dim3 gg(S / 64, E / 64), bb(256);
  gemm_xwT<<<gg, bb, 0, stream>>>(query, wq, bq, qp, S, E, E);
  gemm_xwT<<<gg, bb, 0, stream>>>(key,   wk, bk, kp, S, E, E);
  gemm_xwT<<<gg, bb, 0, stream>>>(value, wv, bv, vp, S, E, E);

  for (int h0 = 0; h0 < NH; h0 += nhb) {
    const int nh = (NH - h0 < nhb) ? (NH - h0) : nhb;
    score_qkT<<<dim3(S / 64, S / 64, nh), bb, 0, stream>>>(qp, kp, sc, h0);
    select_rows<<<dim3(S / 4, nh), bb, 0, stream>>>(sc, vp, query, key, wq, wk,
                                                    ctx, am, h0);
  }

  gemm_xwT<<<gg, bb, 0, stream>>>(ctx, wo, bo, out, S, E, E);
}

// Round 5
// 796.542 us; speedup vs baseline: 5.3867x; 1.2414x over previous
//
#include <hip/hip_runtime.h>
#include <cstdint>

#define S 2048
#define E 1024
#define NH 16
#define HD 64
#define KTOP 32
#define BANDU 1e-3f       // unscaled-score ambiguity band (~77 sigma of fp32 err)
#define NPMAX 48

// ---------------- fp32 GEMM: C[M,N] = X[M,K] @ W[N,K]^T + bias ----------------
__global__ __launch_bounds__(256)
void gemm_xwT(const float* __restrict__ X, const float* __restrict__ W,
              const float* __restrict__ bias, float* __restrict__ C,
              int M, int N, int K) {
  __shared__ float Xs[16][68];
  __shared__ float Ws[16][68];
  const int bm = blockIdx.x * 64;
  const int bn = blockIdx.y * 64;
  const int tid = threadIdx.x;
  const int tx = tid & 15, ty = tid >> 4;
  const int r = tid & 63, kk = (tid >> 6) * 4;
  float acc[4][4] = {};
  for (int k0 = 0; k0 < K; k0 += 16) {
    __syncthreads();
    {
      float4 xv = *(const float4*)(X + (size_t)(bm + r) * K + k0 + kk);
      Xs[kk + 0][r] = xv.x; Xs[kk + 1][r] = xv.y;
      Xs[kk + 2][r] = xv.z; Xs[kk + 3][r] = xv.w;
      float4 wv4 = *(const float4*)(W + (size_t)(bn + r) * K + k0 + kk);
      Ws[kk + 0][r] = wv4.x; Ws[kk + 1][r] = wv4.y;
      Ws[kk + 2][r] = wv4.z; Ws[kk + 3][r] = wv4.w;
    }
    __syncthreads();
#pragma unroll
    for (int k = 0; k < 16; ++k) {
      float4 a = *(const float4*)&Xs[k][tx * 4];
      float4 b = *(const float4*)&Ws[k][ty * 4];
      float av[4] = {a.x, a.y, a.z, a.w};
      float bv[4] = {b.x, b.y, b.z, b.w};
#pragma unroll
      for (int i = 0; i < 4; ++i)
#pragma unroll
        for (int j = 0; j < 4; ++j)
          acc[i][j] = fmaf(av[i], bv[j], acc[i][j]);
    }
  }
  const float4 bv4 = *(const float4*)(bias + bn + ty * 4);
  const float bb[4] = {bv4.x, bv4.y, bv4.z, bv4.w};
#pragma unroll
  for (int i = 0; i < 4; ++i) {
    float4 o;
    o.x = acc[i][0] + bb[0];
    o.y = acc[i][1] + bb[1];
    o.z = acc[i][2] + bb[2];
    o.w = acc[i][3] + bb[3];
    *(float4*)(C + (size_t)(bm + tx * 4 + i) * N + bn + ty * 4) = o;
  }
}

// -------- score GEMM per head: Sc[hz][i][j] = Q_h[i,:].K_h[j,:], K=64 ---------
__global__ __launch_bounds__(256)
void score_qkT(const float* __restrict__ QP, const float* __restrict__ KP,
               float* __restrict__ Sc, int h0) {
  const float* A = QP + (size_t)(h0 + blockIdx.z) * HD;
  const float* B = KP + (size_t)(h0 + blockIdx.z) * HD;
  float* C = Sc + (size_t)blockIdx.z * S * S;
  __shared__ float Xs[16][68];
  __shared__ float Ws[16][68];
  const int bm = blockIdx.x * 64;
  const int bn = blockIdx.y * 64;
  const int tid = threadIdx.x;
  const int tx = tid & 15, ty = tid >> 4;
  const int r = tid & 63, kk = (tid >> 6) * 4;
  float acc[4][4] = {};
#pragma unroll
  for (int k0 = 0; k0 < HD; k0 += 16) {
    __syncthreads();
    {
      float4 xv = *(const float4*)(A + (size_t)(bm + r) * E + k0 + kk);
      Xs[kk + 0][r] = xv.x; Xs[kk + 1][r] = xv.y;
      Xs[kk + 2][r] = xv.z; Xs[kk + 3][r] = xv.w;
      float4 wv4 = *(const float4*)(B + (size_t)(bn + r) * E + k0 + kk);
      Ws[kk + 0][r] = wv4.x; Ws[kk + 1][r] = wv4.y;
      Ws[kk + 2][r] = wv4.z; Ws[kk + 3][r] = wv4.w;
    }
    __syncthreads();
#pragma unroll
    for (int k = 0; k < 16; ++k) {
      float4 a = *(const float4*)&Xs[k][tx * 4];
      float4 b = *(const float4*)&Ws[k][ty * 4];
      float av[4] = {a.x, a.y, a.z, a.w};
      float bv[4] = {b.x, b.y, b.z, b.w};
#pragma unroll
      for (int i = 0; i < 4; ++i)
#pragma unroll
        for (int j = 0; j < 4; ++j)
          acc[i][j] = fmaf(av[i], bv[j], acc[i][j]);
    }
  }
#pragma unroll
  for (int i = 0; i < 4; ++i) {
    float4 o;
    o.x = acc[i][0]; o.y = acc[i][1]; o.z = acc[i][2]; o.w = acc[i][3];
    *(float4*)(C + (size_t)(bm + tx * 4 + i) * S + bn + ty * 4) = o;
  }
}

// ------------------------------ helpers --------------------------------------
__device__ __forceinline__ unsigned fordu(float x) {
  unsigned u = __float_as_uint(x);
  return (u & 0x80000000u) ? ~u : (u | 0x80000000u);
}
__device__ __forceinline__ float invfordu(unsigned f) {
  unsigned u = (f & 0x80000000u) ? (f ^ 0x80000000u) : ~f;
  return __uint_as_float(u);
}
__device__ __forceinline__ unsigned long long fordu64(double x) {
  unsigned long long u = (unsigned long long)__double_as_longlong(x);
  return (u >> 63) ? ~u : (u | 0x8000000000000000ULL);
}
__device__ __forceinline__ unsigned long long shflx64(unsigned long long v, int off) {
  int lo = __shfl_xor((int)(unsigned)(v & 0xFFFFFFFFULL), off);
  int hi = __shfl_xor((int)(unsigned)(v >> 32), off);
  return ((unsigned long long)(unsigned)hi << 32) | (unsigned)lo;
}
__device__ __forceinline__ double shflx_f64(double v, int off) {
  unsigned long long u = (unsigned long long)__double_as_longlong(v);
  return __longlong_as_double((long long)shflx64(u, off));
}
// fp64 projection element: sum_e x[e]*w[e] (rare band path)
__device__ double proj64(const float* __restrict__ xrow, const float* __restrict__ wrow) {
  double a0 = 0.0, a1 = 0.0;
  for (int e = 0; e < E; e += 8) {
    const float4 x0 = *(const float4*)(xrow + e);
    const float4 w0 = *(const float4*)(wrow + e);
    const float4 x1 = *(const float4*)(xrow + e + 4);
    const float4 w1 = *(const float4*)(wrow + e + 4);
    a0 = fma((double)x0.x, (double)w0.x, a0);
    a0 = fma((double)x0.y, (double)w0.y, a0);
    a0 = fma((double)x0.z, (double)w0.z, a0);
    a0 = fma((double)x0.w, (double)w0.w, a0);
    a1 = fma((double)x1.x, (double)w1.x, a1);
    a1 = fma((double)x1.y, (double)w1.y, a1);
    a1 = fma((double)x1.z, (double)w1.z, a1);
    a1 = fma((double)x1.w, (double)w1.w, a1);
  }
  return a0 + a1;
}

// ---- select: threshold+compact+sort exact top-k + band fp64 + softmax + ctx --
__global__ __launch_bounds__(256)
void select_rows(const float* __restrict__ Sc, const float* __restrict__ VP,
                 const float* __restrict__ QRAW, const float* __restrict__ KRAW,
                 const float* __restrict__ WQ, const float* __restrict__ WK,
                 float* __restrict__ CTX, float* __restrict__ AM, int h0) {
  __shared__ unsigned long long cand[4][64];
  const int h = h0 + blockIdx.y;
  const int wid = threadIdx.x >> 6;
  const int row = blockIdx.x * 4 + wid;
  const int lane = threadIdx.x & 63;
  const float* srow = Sc + (size_t)blockIdx.y * S * S + (size_t)row * S;

  // lane holds 32 scores: idx(i,c) = i*256 + lane*4 + c  (coalesced float4)
  float4 g[8];
#pragma unroll
  for (int i = 0; i < 8; ++i) g[i] = *(const float4*)(srow + i * 256 + lane * 4);
  float gm[8];
#pragma unroll
  for (int i = 0; i < 8; ++i)
    gm[i] = fmaxf(fmaxf(g[i].x, g[i].y), fmaxf(g[i].z, g[i].w));
  float lm = fmaxf(fmaxf(fmaxf(gm[0], gm[1]), fmaxf(gm[2], gm[3])),
                   fmaxf(fmaxf(gm[4], gm[5]), fmaxf(gm[6], gm[7])));

  // ---- threshold T = 34th-largest lane-max (guarantees top-34 coverage) ----
  float sk = lm;
#pragma unroll
  for (int k = 2; k <= 64; k <<= 1)
#pragma unroll
    for (int j = k >> 1; j; j >>= 1) {
      const float o = __shfl_xor(sk, j);
      const float mx = fmaxf(sk, o), mn = fminf(sk, o);
      const bool up = ((lane & k) == 0);
      sk = (((lane & j) == 0) == up) ? mx : mn;
    }
  const float T = __shfl(sk, 33);

  // ---- count & prefix-sum candidates (v >= T) ----
  int cnt = 0;
#pragma unroll
  for (int i = 0; i < 8; ++i)
    cnt += (g[i].x >= T) + (g[i].y >= T) + (g[i].z >= T) + (g[i].w >= T);
  int pre = cnt;
#pragma unroll
  for (int off = 1; off < 64; off <<= 1) {
    const int y = __shfl_up(pre, off);
    if (lane >= off) pre += y;
  }
  const int n = __shfl(pre, 63);

  float mv = -INFINITY; int mi = 0;
  if (n <= 64) {
    // ---- compact into per-wave LDS, then one u64 bitonic sort ----
    cand[wid][lane] = 0ULL;
    __threadfence_block();
    int pos = pre - cnt;
#pragma unroll
    for (int i = 0; i < 8; ++i) {
      const int b = i * 256 + lane * 4;
      if (g[i].x >= T) cand[wid][pos++] = (((unsigned long long)fordu(g[i].x)) << 32) | (unsigned)(2047 - (b + 0));
      if (g[i].y >= T) cand[wid][pos++] = (((unsigned long long)fordu(g[i].y)) << 32) | (unsigned)(2047 - (b + 1));
      if (g[i].z >= T) cand[wid][pos++] = (((unsigned long long)fordu(g[i].z)) << 32) | (unsigned)(2047 - (b + 2));
      if (g[i].w >= T) cand[wid][pos++] = (((unsigned long long)fordu(g[i].w)) << 32) | (unsigned)(2047 - (b + 3));
    }
    __threadfence_block();
    unsigned long long key = cand[wid][lane];
#pragma unroll
    for (int k = 2; k <= 64; k <<= 1)
#pragma unroll
      for (int j = k >> 1; j; j >>= 1) {
        const unsigned long long o = shflx64(key, j);
        const unsigned long long mx = key > o ? key : o;
        const unsigned long long mn = key > o ? o : key;
        const bool up = ((lane & k) == 0);
        key = (((lane & j) == 0) == up) ? mx : mn;
      }
    if (lane < n) {
      mv = invfordu((unsigned)(key >> 32));
      mi = 2047 - (int)(key & 0xFFFFFFFFu);
    }
  } else {
    // ---- rare fallback (massive ties): exact pop-max loop (round-4 path) ----
    float v32f = -INFINITY, v33f = -INFINITY;
    bool stop = false;
#pragma unroll 1
    for (int p = 0; p < NPMAX && !stop; ++p) {
      float M = lm;
#pragma unroll
      for (int off = 32; off; off >>= 1) M = fmaxf(M, __shfl_xor(M, off));
      int fp = 0x7FFFFFFF;
#pragma unroll
      for (int i = 7; i >= 0; --i) {
        const int b = i * 256 + lane * 4;
        if (g[i].w == M) fp = b + 3;
        if (g[i].z == M) fp = b + 2;
        if (g[i].y == M) fp = b + 1;
        if (g[i].x == M) fp = b + 0;
      }
      const unsigned long long bal = __ballot(lm == M);
      int widx;
      if (__popcll(bal) == 1) {
        widx = __shfl(fp, __ffsll(bal) - 1);
      } else {
        int c2 = (lm == M) ? fp : 0x7FFFFFFF;
#pragma unroll
        for (int off = 32; off; off >>= 1) c2 = min(c2, __shfl_xor(c2, off));
        widx = c2;
      }
      const int ol = (widx >> 2) & 63, og = widx >> 8, oc = widx & 3;
      const bool own = (lane == ol);
#pragma unroll
      for (int i = 0; i < 8; ++i)
        if (og == i && own) {
          if (oc == 0) g[i].x = -INFINITY;
          else if (oc == 1) g[i].y = -INFINITY;
          else if (oc == 2) g[i].z = -INFINITY;
          else g[i].w = -INFINITY;
          gm[i] = fmaxf(fmaxf(g[i].x, g[i].y), fmaxf(g[i].z, g[i].w));
        }
      float m8 = fmaxf(fmaxf(fmaxf(gm[0], gm[1]), fmaxf(gm[2], gm[3])),
                       fmaxf(fmaxf(gm[4], gm[5]), fmaxf(gm[6], gm[7])));
      lm = own ? m8 : lm;
      if (lane == p) { mv = M; mi = widx; }
      if (p == 33) {
        v32f = __shfl(mv, 31); v33f = __shfl(mv, 32);
        stop = (v32f - v33f > BANDU);
      } else if (p > 33) {
        stop = (M < v32f - BANDU);
      }
    }
  }

  const float v32 = __shfl(mv, 31), v33 = __shfl(mv, 32);
  bool IN = (lane < KTOP);
  if (v32 - v33 <= BANDU) {   // ambiguous cut (rare, wave-uniform)
    const bool flg = (mv >= v32 - BANDU) && (mv <= v33 + BANDU);
    const unsigned long long fmask = __ballot(flg);
    const int nAbove = __popcll(__ballot((lane < KTOP) && !flg));
    const int need = KTOP - nAbove;
    const double qd = proj64(QRAW + (size_t)row * E, WQ + (size_t)(h * HD + lane) * E);
    double s64 = -INFINITY;
    unsigned long long t = fmask;
    while (t) {
      const int f = __ffsll(t) - 1; t &= t - 1;
      const int ki = __shfl(mi, f);
      const double kd = proj64(KRAW + (size_t)ki * E, WK + (size_t)(h * HD + lane) * E);
      double sacc = qd * kd;
#pragma unroll
      for (int off = 32; off; off >>= 1) sacc += shflx_f64(sacc, off);
      if (lane == f) s64 = sacc;
    }
    bool in2 = false;
    for (int t2 = 0; t2 < need; ++t2) {
      const unsigned long long sk2 = (flg && !in2) ? fordu64(s64) : 0ULL;
      unsigned long long mx = sk2;
#pragma unroll
      for (int off = 32; off; off >>= 1) {
        const unsigned long long o = shflx64(mx, off);
        if (o > mx) mx = o;
      }
      const unsigned long long wb = __ballot(flg && !in2 && sk2 == mx);
      if (lane == __ffsll(wb) - 1) in2 = true;
    }
    IN = ((lane < KTOP) && !flg) || in2;
  }

  // softmax over IN (unscaled scores; scale 1/8 inside exp)
  float x = IN ? mv : -INFINITY, m = x;
#pragma unroll
  for (int off = 32; off; off >>= 1) m = fmaxf(m, __shfl_xor(m, off));
  const float ee = IN ? expf((mv - m) * 0.125f) : 0.f;
  float z = ee;
#pragma unroll
  for (int off = 32; off; off >>= 1) z += __shfl_xor(z, off);
  const float w = ee / z;
  if (IN) atomicAdd(AM + (size_t)row * S + mi, w * 0.0625f);

  unsigned long long mask = __ballot(IN);
  float acc = 0.f;
  while (mask) {
    const int b = __ffsll(mask) - 1; mask &= mask - 1;
    const float wi = __shfl(w, b);
    const int ii = __shfl(mi, b);
    acc = fmaf(wi, VP[(size_t)ii * E + h * HD + lane], acc);
  }
  CTX[(size_t)row * E + h * HD + lane] = acc;
}

extern "C" void kernel_launch(void* const* d_in, const int* in_sizes, int n_in,
                              void* d_out, int out_size, void* d_ws, size_t ws_size,
                              hipStream_t stream) {
  const float* query = (const float*)d_in[0];
  const float* key   = (const float*)d_in[1];
  const float* value = (const float*)d_in[2];
  const float* wq = (const float*)d_in[3];
  const float* bq = (const float*)d_in[4];
  const float* wk = (const float*)d_in[5];
  const float* bk = (const float*)d_in[6];
  const float* wv = (const float*)d_in[7];
  const float* bv = (const float*)d_in[8];
  const float* wo = (const float*)d_in[9];
  const float* bo = (const float*)d_in[10];

  float* out = (float*)d_out;                 // [S, E]
  float* am  = out + (size_t)S * E;           // [S, S]
  float* qp  = (float*)d_ws;                  // [S, E]
  float* kp  = qp + (size_t)S * E;
  float* vp  = kp + (size_t)S * E;
  float* ctx = vp + (size_t)S * E;
  float* sc  = ctx + (size_t)S * E;           // score buffer (chunked by heads)

  const size_t base = 4ull * S * E * sizeof(float);
  const size_t per_head = (size_t)S * S * sizeof(float);
  int nhb = (ws_size > base) ? (int)((ws_size - base) / per_head) : 0;
  if (nhb < 1) nhb = 1;
  if (nhb > NH) nhb = NH;

  hipMemsetAsync(am, 0, (size_t)S * S * sizeof(float), stream);

  const dim3 gg(S / 64, E / 64), bb(256);
  gemm_xwT<<<gg, bb, 0, stream>>>(query, wq, bq, qp, S, E, E);
  gemm_xwT<<<gg, bb, 0, stream>>>(key,   wk, bk, kp, S, E, E);
  gemm_xwT<<<gg, bb, 0, stream>>>(value, wv, bv, vp, S, E, E);

  for (int h0 = 0; h0 < NH; h0 += nhb) {
    const int nh = (NH - h0 < nhb) ? (NH - h0) : nhb;
    score_qkT<<<dim3(S / 64, S / 64, nh), bb, 0, stream>>>(qp, kp, sc, h0);
    select_rows<<<dim3(S / 4, nh), bb, 0, stream>>>(sc, vp, query, key, wq, wk,
                                                    ctx, am, h0);
  }

  gemm_xwT<<<gg, bb, 0, stream>>>(ctx, wo, bo, out, S, E, E);
}